// Round 1
// baseline (81.575 us; speedup 1.0000x reference)
//
#include <hip/hip_runtime.h>

// RhythmNetLoss: out = mean(|a-b|) + 150 * mean(|x - mean(x)|), x = a[:6].flatten()
// a,b: (8192,4096) fp32. Output: 1 fp32 scalar.

#define N_TOTAL  (8192 * 4096)
#define N_SMOOTH (6 * 4096)
#define LAMBDA_F 150.0f

constexpr int BLOCKS  = 2048;
constexpr int THREADS = 256;

// Block-wide sum + broadcast. Assumes blockDim.x == 256 (4 waves of 64).
__device__ __forceinline__ float block_reduce_bcast(float v) {
    __shared__ float ws[5];
    __syncthreads();  // protect ws across repeated calls
    #pragma unroll
    for (int off = 32; off > 0; off >>= 1) v += __shfl_down(v, off, 64);
    const int lane = threadIdx.x & 63;
    const int wid  = threadIdx.x >> 6;
    if (lane == 0) ws[wid] = v;
    __syncthreads();
    if (threadIdx.x == 0) ws[4] = ws[0] + ws[1] + ws[2] + ws[3];
    __syncthreads();
    return ws[4];
}

// Kernel A: partial sums of |a-b| over the full tensor, float4-vectorized.
__global__ __launch_bounds__(THREADS) void l1_partial_kernel(
    const float4* __restrict__ a, const float4* __restrict__ b,
    float* __restrict__ partial) {
    const int n4     = N_TOTAL / 4;
    const int tid    = blockIdx.x * blockDim.x + threadIdx.x;
    const int stride = gridDim.x * blockDim.x;
    float s = 0.0f;
    for (int i = tid; i < n4; i += stride) {
        float4 va = a[i];
        float4 vb = b[i];
        s += fabsf(va.x - vb.x) + fabsf(va.y - vb.y) +
             fabsf(va.z - vb.z) + fabsf(va.w - vb.w);
    }
    float bs = block_reduce_bcast(s);
    if (threadIdx.x == 0) partial[blockIdx.x] = bs;
}

// Kernel B: reduce partials -> l1 sum; two tiny passes over first 6 rows
// for the smooth term; write the final scalar.
__global__ __launch_bounds__(THREADS) void finalize_kernel(
    const float* __restrict__ partial, const float* __restrict__ gru,
    float* __restrict__ out) {
    // 1) total |a-b| sum
    float s = 0.0f;
    for (int i = threadIdx.x; i < BLOCKS; i += THREADS) s += partial[i];
    float l1_sum = block_reduce_bcast(s);

    // 2) mean of x = gru[0 : 24576]
    float xs = 0.0f;
    for (int i = threadIdx.x; i < N_SMOOTH; i += THREADS) xs += gru[i];
    float x_sum = block_reduce_bcast(xs);
    float x_mean = x_sum / (float)N_SMOOTH;

    // 3) sum |x - mean|
    float ds = 0.0f;
    for (int i = threadIdx.x; i < N_SMOOTH; i += THREADS) ds += fabsf(gru[i] - x_mean);
    float dev_sum = block_reduce_bcast(ds);

    if (threadIdx.x == 0) {
        float l1     = l1_sum / (float)N_TOTAL;
        float smooth = dev_sum / (float)N_SMOOTH;
        out[0] = l1 + LAMBDA_F * smooth;
    }
}

extern "C" void kernel_launch(void* const* d_in, const int* in_sizes, int n_in,
                              void* d_out, int out_size, void* d_ws, size_t ws_size,
                              hipStream_t stream) {
    const float* gru = (const float*)d_in[0];
    const float* tgt = (const float*)d_in[1];
    float* out     = (float*)d_out;
    float* partial = (float*)d_ws;  // BLOCKS floats = 8 KB

    l1_partial_kernel<<<BLOCKS, THREADS, 0, stream>>>(
        (const float4*)gru, (const float4*)tgt, partial);
    finalize_kernel<<<1, THREADS, 0, stream>>>(partial, gru, out);
}

// Round 2
// 48.187 us; speedup vs baseline: 1.6929x; 1.6929x over previous
//
#include <hip/hip_runtime.h>

// RhythmNetLoss: out = mean(|a-b|) + 150 * mean(|x - mean(x)|), x = a[:6].flatten()
// a,b: (8192,4096) fp32. Output: 1 fp32 scalar.

#define N_TOTAL  (8192 * 4096)
#define N_SMOOTH (6 * 4096)
#define LAMBDA_F 150.0f

constexpr int BLOCKS  = 2048;
constexpr int THREADS = 256;
constexpr int N4           = N_TOTAL / 4;        // 8388608 float4
constexpr int F4_PER_BLOCK = N4 / BLOCKS;        // 4096 (64 KiB per input per block)
constexpr int ITERS        = F4_PER_BLOCK / THREADS; // 16 float4 per thread
constexpr int FT = 1024;                         // finalize block size

// Block-wide sum + broadcast. NT = blockDim.x (multiple of 64).
template <int NT>
__device__ __forceinline__ float block_reduce_bcast(float v) {
    __shared__ float ws[NT / 64 + 1];
    __syncthreads();  // protect ws across repeated calls
    #pragma unroll
    for (int off = 32; off > 0; off >>= 1) v += __shfl_down(v, off, 64);
    const int lane = threadIdx.x & 63;
    const int wid  = threadIdx.x >> 6;
    if (lane == 0) ws[wid] = v;
    __syncthreads();
    if (threadIdx.x == 0) {
        float s = 0.0f;
        #pragma unroll
        for (int w = 0; w < NT / 64; ++w) s += ws[w];
        ws[NT / 64] = s;
    }
    __syncthreads();
    return ws[NT / 64];
}

__device__ __forceinline__ float abs4(float4 va, float4 vb) {
    return fabsf(va.x - vb.x) + fabsf(va.y - vb.y) +
           fabsf(va.z - vb.z) + fabsf(va.w - vb.w);
}

// Kernel A: partial sums of |a-b|, 4 float4/input in flight per group.
__global__ __launch_bounds__(THREADS) void l1_partial_kernel(
    const float4* __restrict__ a, const float4* __restrict__ b,
    float* __restrict__ partial) {
    const int base = blockIdx.x * F4_PER_BLOCK + threadIdx.x;
    float s0 = 0.0f, s1 = 0.0f, s2 = 0.0f, s3 = 0.0f;
    #pragma unroll
    for (int g = 0; g < ITERS / 4; ++g) {
        const int i0 = base + (g * 4 + 0) * THREADS;
        const int i1 = base + (g * 4 + 1) * THREADS;
        const int i2 = base + (g * 4 + 2) * THREADS;
        const int i3 = base + (g * 4 + 3) * THREADS;
        float4 a0 = a[i0]; float4 a1 = a[i1]; float4 a2 = a[i2]; float4 a3 = a[i3];
        float4 b0 = b[i0]; float4 b1 = b[i1]; float4 b2 = b[i2]; float4 b3 = b[i3];
        s0 += abs4(a0, b0);
        s1 += abs4(a1, b1);
        s2 += abs4(a2, b2);
        s3 += abs4(a3, b3);
    }
    float bs = block_reduce_bcast<THREADS>((s0 + s1) + (s2 + s3));
    if (threadIdx.x == 0) partial[blockIdx.x] = bs;
}

// Kernel B: reduce partials; two vectorized passes over first 6 rows; write scalar.
__global__ __launch_bounds__(FT) void finalize_kernel(
    const float* __restrict__ partial, const float* __restrict__ gru,
    float* __restrict__ out) {
    // 1) total |a-b| sum
    float s = 0.0f;
    #pragma unroll
    for (int i = threadIdx.x; i < BLOCKS; i += FT) s += partial[i];
    float l1_sum = block_reduce_bcast<FT>(s);

    // 2) mean of x = gru[0 : 24576], float4-vectorized
    const float4* x4 = (const float4*)gru;
    constexpr int NS4 = N_SMOOTH / 4;  // 6144
    float xs = 0.0f;
    #pragma unroll
    for (int i = threadIdx.x; i < NS4; i += FT) {
        float4 v = x4[i];
        xs += (v.x + v.y) + (v.z + v.w);
    }
    float x_mean = block_reduce_bcast<FT>(xs) / (float)N_SMOOTH;

    // 3) sum |x - mean| (x now L1/L2-resident)
    float ds = 0.0f;
    #pragma unroll
    for (int i = threadIdx.x; i < NS4; i += FT) {
        float4 v = x4[i];
        ds += fabsf(v.x - x_mean) + fabsf(v.y - x_mean) +
              fabsf(v.z - x_mean) + fabsf(v.w - x_mean);
    }
    float dev_sum = block_reduce_bcast<FT>(ds);

    if (threadIdx.x == 0) {
        out[0] = l1_sum / (float)N_TOTAL + LAMBDA_F * (dev_sum / (float)N_SMOOTH);
    }
}

extern "C" void kernel_launch(void* const* d_in, const int* in_sizes, int n_in,
                              void* d_out, int out_size, void* d_ws, size_t ws_size,
                              hipStream_t stream) {
    const float* gru = (const float*)d_in[0];
    const float* tgt = (const float*)d_in[1];
    float* out     = (float*)d_out;
    float* partial = (float*)d_ws;  // BLOCKS floats = 8 KB

    l1_partial_kernel<<<BLOCKS, THREADS, 0, stream>>>(
        (const float4*)gru, (const float4*)tgt, partial);
    finalize_kernel<<<1, FT, 0, stream>>>(partial, gru, out);
}